// Round 5
// baseline (129.901 us; speedup 1.0000x reference)
//
#include <hip/hip_runtime.h>

// Problem constants: B=1024, F=33, D=128, A=128, P=F*(F-1)/2=528
#define FN 33
#define DN 128
#define AN 128
#define PN 528
#define XS 136     // fp16 row stride for xh in LDS (272 B, 16B-aligned, non-pow2)
#define TS 36      // float row stride for attn2d (144 B)

typedef __attribute__((ext_vector_type(8))) _Float16 half8;
typedef __attribute__((ext_vector_type(4))) float f32x4;
typedef __attribute__((ext_vector_type(4))) unsigned int u32x4;

__device__ __forceinline__ unsigned int pkrtz(float a, float b) {
  return __builtin_bit_cast(unsigned int, __builtin_amdgcn_cvt_pkrtz(a, b));
}

// sum over the 16-lane DPP row via row_ror rotations (VALU pipe, no LDS)
__device__ __forceinline__ float row_sum16(float v) {
  v += __builtin_bit_cast(float, __builtin_amdgcn_update_dpp(0, __builtin_bit_cast(int, v), 0x128, 0xF, 0xF, false));
  v += __builtin_bit_cast(float, __builtin_amdgcn_update_dpp(0, __builtin_bit_cast(int, v), 0x124, 0xF, 0xF, false));
  v += __builtin_bit_cast(float, __builtin_amdgcn_update_dpp(0, __builtin_bit_cast(int, v), 0x122, 0xF, 0xF, false));
  v += __builtin_bit_cast(float, __builtin_amdgcn_update_dpp(0, __builtin_bit_cast(int, v), 0x121, 0xF, 0xF, false));
  return v;
}

// ---- staging: issue x loads early (pinned), convert+store later ------------
#define XLOAD(XV, XT, BB)                                                     \
  {                                                                           \
    const f32x4* xb = (const f32x4*)(xg + (size_t)(BB) * FN * DN);            \
    _Pragma("unroll")                                                         \
    for (int s = 0; s < 4; s++) {                                             \
      XV[s] = xb[tid + s * 256];                                              \
      asm volatile("" : "+v"(XV[s]));                                         \
    }                                                                         \
    if (tid < 32) XT = xb[1024 + tid];                                        \
    asm volatile("" : "+v"(XT));                                              \
  }

#define XSTORE(XV, XT, BUFI)                                                  \
  {                                                                           \
    _Pragma("unroll")                                                         \
    for (int s = 0; s < 4; s++) {                                             \
      const int idx = tid + s * 256;                                          \
      const int i = idx >> 5, d0 = (idx & 31) << 2;                           \
      *(uint2*)&xh[BUFI][i * XS + d0] =                                       \
          make_uint2(pkrtz(XV[s].x, XV[s].y), pkrtz(XV[s].z, XV[s].w));       \
    }                                                                         \
    if (tid < 32) {                                                           \
      const int idx = 1024 + tid;                                             \
      const int i = idx >> 5, d0 = (idx & 31) << 2;                           \
      *(uint2*)&xh[BUFI][i * XS + d0] =                                       \
          make_uint2(pkrtz(XT.x, XT.y), pkrtz(XT.z, XT.w));                   \
    }                                                                         \
  }

// ---- WALK: fm matmul + score partials + in-walk wave-max of partials -------
#define WALK(XHB, GB, SPB, RMAXP)                                             \
  {                                                                           \
    const int t_beg = mh ? 17 : 0;                                            \
    const int t_end = mh ? 33 : 17;                                           \
    float wm = -3.4e38f;                                                      \
    unsigned int rc_next = rowcol[t_beg * 16 + u];                            \
    for (int t = t_beg; t < t_end; ++t) {                                     \
      const unsigned int rc = rc_next;                                        \
      if (t + 1 < t_end) rc_next = rowcol[(t + 1) * 16 + u];                  \
      const int r = rc & 255, c = rc >> 8;                                    \
      const _Float16* xr_base = &XHB[r * XS + q * 8];                         \
      const _Float16* xc_base = &XHB[c * XS + q * 8];                         \
      f32x4 acc[4];                                                           \
      _Pragma("unroll")                                                       \
      for (int nn = 0; nn < 4; nn++) acc[nn] = (f32x4){0.f, 0.f, 0.f, 0.f};   \
      __builtin_amdgcn_s_setprio(1);                                          \
      _Pragma("unroll")                                                       \
      for (int kk = 0; kk < 4; kk++) {                                        \
        half8 af = *(const half8*)(xr_base + kk * 32) *                       \
                   *(const half8*)(xc_base + kk * 32);                        \
        _Pragma("unroll")                                                     \
        for (int nn = 0; nn < 4; nn++)                                        \
          acc[nn] = __builtin_amdgcn_mfma_f32_16x16x32_f16(af, Bf[nn][kk],    \
                                                           acc[nn], 0, 0, 0);  \
      }                                                                       \
      __builtin_amdgcn_s_setprio(0);                                          \
      float sc[4] = {0.f, 0.f, 0.f, 0.f};                                     \
      _Pragma("unroll")                                                       \
      for (int nn = 0; nn < 4; nn++)                                          \
        _Pragma("unroll")                                                     \
        for (int rr = 0; rr < 4; rr++)                                        \
          sc[rr] = fmaf(fmaxf(acc[nn][rr] + barr[nn], 0.f), GB[nn], sc[rr]);  \
      _Pragma("unroll")                                                       \
      for (int rr = 0; rr < 4; rr++) sc[rr] = row_sum16(sc[rr]);              \
      wm = fmaxf(wm, fmaxf(fmaxf(sc[0], sc[1]), fmaxf(sc[2], sc[3])));        \
      if (u == 0)                                                             \
        *(f32x4*)&SPB[t * 16 + q * 4] = (f32x4){sc[0], sc[1], sc[2], sc[3]};  \
    }                                                                         \
    wm = fmaxf(wm, __shfl_xor(wm, 16, 64));                                   \
    wm = fmaxf(wm, __shfl_xor(wm, 32, 64));                                   \
    if (lane == 0) RMAXP[wave] = wm;                                          \
  }

// ---- S: exp with upper-bound shift M^ = max(sp0)+max(sp1), scatter, sum ----
// Uniform shift >= true max: softmax ratio exact; overshoot only scales by
// e^-delta (delta ~ 10-15 here, harmless in fp32).
#define SPH(PARM)                                                             \
  {                                                                           \
    const float Mh = fmaxf(rmax[PARM][0], rmax[PARM][2]) +                    \
                     fmaxf(rmax[PARM][1], rmax[PARM][3]);                     \
    float s0 = sp[PARM][0][tid] + sp[PARM][1][tid];                           \
    float s1 = sp[PARM][0][tid + 256] + sp[PARM][1][tid + 256];               \
    float e0 = __expf(s0 - Mh);                                               \
    float e1 = __expf(s1 - Mh);                                               \
    unsigned int rc = rowcol[tid];                                            \
    attn2d[PARM][(rc & 255) * TS + ((rc >> 8) - (rc & 255) - 1)] = e0;        \
    rc = rowcol[tid + 256];                                                   \
    attn2d[PARM][(rc & 255) * TS + ((rc >> 8) - (rc & 255) - 1)] = e1;        \
    float e2 = 0.f;                                                           \
    if (tid < 16) {                                                           \
      float s2 = sp[PARM][0][tid + 512] + sp[PARM][1][tid + 512];             \
      e2 = __expf(s2 - Mh);                                                   \
      rc = rowcol[tid + 512];                                                 \
      attn2d[PARM][(rc & 255) * TS + ((rc >> 8) - (rc & 255) - 1)] = e2;      \
    }                                                                         \
    float ls = (e0 + e1) + e2;                                                \
    _Pragma("unroll")                                                         \
    for (int off = 32; off >= 1; off >>= 1) ls += __shfl_xor(ls, off, 64);    \
    if (lane == 0) rsum[PARM][wave] = ls;                                     \
  }

// ---- E: barrier-free epilogue. tid<128: full 528-FMA chain for d=tid and
// direct out write; tid>=128: gnn passthrough. No part[], no out-barrier. ----
#define EPH(PARM, XHB, BB)                                                    \
  if (tid < 128) {                                                            \
    const float Zb = (rsum[PARM][0] + rsum[PARM][1]) +                        \
                     (rsum[PARM][2] + rsum[PARM][3]);                         \
    const int d = tid;                                                        \
    float xcol[36];                                                           \
    _Pragma("unroll")                                                         \
    for (int i = 0; i < FN; i++) xcol[i] = (float)XHB[i * XS + d];            \
    xcol[33] = 0.f; xcol[34] = 0.f; xcol[35] = 0.f;                           \
    float accv = 0.f;                                                         \
    _Pragma("unroll")                                                         \
    for (int i = 0; i < 32; i++) {                                            \
      const int L = FN - 1 - i;                                               \
      const int nf4 = (L + 3) >> 2;                                           \
      float ti = 0.f;                                                         \
      _Pragma("unroll")                                                       \
      for (int t = 0; t < nf4; t++) {                                         \
        f32x4 a4 = *(const f32x4*)&attn2d[PARM][i * TS + t * 4];              \
        ti = fmaf(a4.x, xcol[i + 1 + t * 4 + 0], ti);                         \
        ti = fmaf(a4.y, xcol[i + 1 + t * 4 + 1], ti);                         \
        ti = fmaf(a4.z, xcol[i + 1 + t * 4 + 2], ti);                         \
        ti = fmaf(a4.w, xcol[i + 1 + t * 4 + 3], ti);                         \
      }                                                                       \
      accv = fmaf(xcol[i], ti, accv);                                         \
    }                                                                         \
    out[(size_t)(BB) * (AN + DN) + AN + d] = accv * (100.0f / Zb);            \
  } else {                                                                    \
    const int a = tid - 128;                                                  \
    out[(size_t)(BB) * (AN + DN) + a] = gnn[(size_t)(BB) * AN + a];           \
  }

// R5: BPB=4 rolling 3-stage pipeline, grid 256 (1 block/CU). Steady state:
// WALK(b_t) || S(b_{t-1}) || E(b_{t-2}), ONE barrier per iteration.
// 6 barriers / 4 batches (R4: 8 / 2). Max-phase folded into WALK via
// partial-max upper bound; epilogue barrier-free; W/g/bias fetched once.
__global__ __launch_bounds__(256, 1)
void afm_kernel(const float* __restrict__ gnn, const float* __restrict__ xg,
                const float* __restrict__ Wg,  const float* __restrict__ bg,
                float* __restrict__ out)
{
  __shared__ __align__(16) _Float16 xh[4][FN * XS];     // 35.9 KB
  __shared__ __align__(16) float attn2d[2][FN * TS];    // 9.5 KB
  __shared__ __align__(16) float sp[2][2][PN];          // 8.4 KB [par][nh][p]
  __shared__ unsigned short rowcol[PN];                 // 1 KB
  __shared__ float rmax[2][4], rsum[2][4];

  const int tid  = threadIdx.x;
  const int b0   = blockIdx.x * 4;
  const int wave = tid >> 6;
  const int lane = tid & 63;
  const int q    = lane >> 4;   // quad 0..3
  const int u    = lane & 15;
  const int nh   = wave & 1;    // n-half: cols [nh*64, nh*64+64)
  const int mh   = wave >> 1;   // m-half: tiles [0,17) / [17,33)

  // -------- prologue: x loads (b0,b1) first, then W/g/bias -----------------
  f32x4 xv0[4], xv1[4];
  f32x4 xt0 = {0,0,0,0}, xt1 = {0,0,0,0};
  XLOAD(xv0, xt0, b0 + 0);
  XLOAD(xv1, xt1, b0 + 1);

  half8 Bf[4][4];
  float g[4][4], barr[4];
  #pragma unroll
  for (int nn = 0; nn < 4; nn++) {
    const int a = nh * 64 + nn * 16 + u;
    const float* src = Wg + (size_t)a * DN + q * 8;
    #pragma unroll
    for (int kk = 0; kk < 4; kk++) {
      f32x4 w0 = *(const f32x4*)(src + kk * 32);
      f32x4 w1 = *(const f32x4*)(src + kk * 32 + 4);
      u32x4 pk;
      pk.x = pkrtz(w0.x, w0.y);
      pk.y = pkrtz(w0.z, w0.w);
      pk.z = pkrtz(w1.x, w1.y);
      pk.w = pkrtz(w1.z, w1.w);
      Bf[nn][kk] = __builtin_bit_cast(half8, pk);
      asm volatile("" : "+v"(Bf[nn][kk]));   // pin: forbid remat/sinking
    }
    #pragma unroll
    for (int bi = 0; bi < 4; bi++) {
      g[bi][nn] = gnn[(size_t)(b0 + bi) * AN + a];
      asm volatile("" : "+v"(g[bi][nn]));
    }
    barr[nn] = bg[a];
    asm volatile("" : "+v"(barr[nn]));
  }

  // zero attn2d (pads stay 0 forever; real slots rewritten each use)
  {
    float* a2z = &attn2d[0][0];
    for (int idx = tid; idx < 2 * FN * TS; idx += 256) a2z[idx] = 0.0f;
    for (int p = tid; p < PN; p += 256) {
      int i = 0, rem = p;
      while (rem >= FN - 1 - i) { rem -= FN - 1 - i; i++; }
      rowcol[p] = (unsigned short)(i | ((i + 1 + rem) << 8));
    }
  }
  XSTORE(xv0, xt0, 0);
  XSTORE(xv1, xt1, 1);
  __syncthreads();                                      // B0

  // -------- iter0: W(b0) | stage b2 ----------------------------------------
  {
    f32x4 xv2[4], xt2 = {0,0,0,0};
    XLOAD(xv2, xt2, b0 + 2);
    WALK(xh[0], g[0], (&sp[0][nh][0]), rmax[0]);
    XSTORE(xv2, xt2, 2);
  }
  __syncthreads();                                      // B1

  // -------- iter1: W(b1) | S(b0) | stage b3 --------------------------------
  {
    f32x4 xv3[4], xt3 = {0,0,0,0};
    XLOAD(xv3, xt3, b0 + 3);
    WALK(xh[1], g[1], (&sp[1][nh][0]), rmax[1]);
    SPH(0);
    XSTORE(xv3, xt3, 3);
  }
  __syncthreads();                                      // B2

  // -------- iter2: W(b2) | S(b1) | E(b0) -----------------------------------
  WALK(xh[2], g[2], (&sp[0][nh][0]), rmax[0]);
  SPH(1);
  EPH(0, xh[0], b0 + 0);
  __syncthreads();                                      // B3

  // -------- iter3: W(b3) | S(b2) | E(b1) -----------------------------------
  WALK(xh[3], g[3], (&sp[1][nh][0]), rmax[1]);
  SPH(0);
  EPH(1, xh[1], b0 + 1);
  __syncthreads();                                      // B4

  // -------- drain: S(b3) | E(b2) -------------------------------------------
  SPH(1);
  EPH(0, xh[2], b0 + 2);
  __syncthreads();                                      // B5

  EPH(1, xh[3], b0 + 3);
}

extern "C" void kernel_launch(void* const* d_in, const int* in_sizes, int n_in,
                              void* d_out, int out_size, void* d_ws, size_t ws_size,
                              hipStream_t stream) {
  (void)n_in; (void)out_size; (void)d_ws; (void)ws_size;
  const float* gnn  = (const float*)d_in[0];
  const float* x    = (const float*)d_in[1];
  const float* W    = (const float*)d_in[2];
  const float* bias = (const float*)d_in[3];
  float* out = (float*)d_out;
  const int Bn = in_sizes[0] / AN;   // 1024
  afm_kernel<<<dim3(Bn / 4), dim3(256), 0, stream>>>(gnn, x, W, bias, out);
}

// Round 6
// 107.919 us; speedup vs baseline: 1.2037x; 1.2037x over previous
//
#include <hip/hip_runtime.h>

// Problem constants: B=1024, F=33, D=128, A=128, P=F*(F-1)/2=528
#define FN 33
#define DN 128
#define AN 128
#define PN 528
#define XS 136     // fp16 row stride for xh in LDS (272 B, 16B-aligned, non-pow2)
#define TS 36      // float row stride for attn2d (144 B)

typedef __attribute__((ext_vector_type(8))) _Float16 half8;
typedef __attribute__((ext_vector_type(4))) float f32x4;
typedef __attribute__((ext_vector_type(4))) unsigned int u32x4;

__device__ __forceinline__ unsigned int pkrtz(float a, float b) {
  return __builtin_bit_cast(unsigned int, __builtin_amdgcn_cvt_pkrtz(a, b));
}

// sum over the 16-lane DPP row via row_ror rotations (VALU pipe, no LDS)
__device__ __forceinline__ float row_sum16(float v) {
  v += __builtin_bit_cast(float, __builtin_amdgcn_update_dpp(0, __builtin_bit_cast(int, v), 0x128, 0xF, 0xF, false));
  v += __builtin_bit_cast(float, __builtin_amdgcn_update_dpp(0, __builtin_bit_cast(int, v), 0x124, 0xF, 0xF, false));
  v += __builtin_bit_cast(float, __builtin_amdgcn_update_dpp(0, __builtin_bit_cast(int, v), 0x122, 0xF, 0xF, false));
  v += __builtin_bit_cast(float, __builtin_amdgcn_update_dpp(0, __builtin_bit_cast(int, v), 0x121, 0xF, 0xF, false));
  return v;
}

// ---- staging: issue x loads early (pinned), convert+store later ------------
#define XLOAD(XV, XT, BB)                                                     \
  {                                                                           \
    const f32x4* xb = (const f32x4*)(xg + (size_t)(BB) * FN * DN);            \
    _Pragma("unroll")                                                         \
    for (int s = 0; s < 4; s++) {                                             \
      XV[s] = xb[tid + s * 256];                                              \
      asm volatile("" : "+v"(XV[s]));                                         \
    }                                                                         \
    if (tid < 32) XT = xb[1024 + tid];                                        \
    asm volatile("" : "+v"(XT));                                              \
  }

#define XSTORE(XV, XT, BUFI)                                                  \
  {                                                                           \
    _Pragma("unroll")                                                         \
    for (int s = 0; s < 4; s++) {                                             \
      const int idx = tid + s * 256;                                          \
      const int i = idx >> 5, d0 = (idx & 31) << 2;                           \
      *(uint2*)&xh[BUFI][i * XS + d0] =                                       \
          make_uint2(pkrtz(XV[s].x, XV[s].y), pkrtz(XV[s].z, XV[s].w));       \
    }                                                                         \
    if (tid < 32) {                                                           \
      const int idx = 1024 + tid;                                             \
      const int i = idx >> 5, d0 = (idx & 31) << 2;                           \
      *(uint2*)&xh[BUFI][i * XS + d0] =                                       \
          make_uint2(pkrtz(XT.x, XT.y), pkrtz(XT.z, XT.w));                   \
    }                                                                         \
  }

// ---- WALK: fm matmul + score partials + in-walk wave-max of partials -------
// Bias folded into acc init (acc = barr broadcast); relu = fmax(acc,0).
#define WALK(XHB, GB, SPB, RMAXP)                                             \
  {                                                                           \
    const int t_beg = mh ? 17 : 0;                                            \
    const int t_end = mh ? 33 : 17;                                           \
    float wm = -3.4e38f;                                                      \
    unsigned int rc_next = rowcol[t_beg * 16 + u];                            \
    for (int t = t_beg; t < t_end; ++t) {                                     \
      const unsigned int rc = rc_next;                                        \
      if (t + 1 < t_end) rc_next = rowcol[(t + 1) * 16 + u];                  \
      const int r = rc & 255, c = rc >> 8;                                    \
      const _Float16* xr_base = &XHB[r * XS + q * 8];                         \
      const _Float16* xc_base = &XHB[c * XS + q * 8];                         \
      f32x4 acc[4];                                                           \
      _Pragma("unroll")                                                       \
      for (int nn = 0; nn < 4; nn++)                                          \
        acc[nn] = (f32x4){barr[nn], barr[nn], barr[nn], barr[nn]};            \
      __builtin_amdgcn_s_setprio(1);                                          \
      _Pragma("unroll")                                                       \
      for (int kk = 0; kk < 4; kk++) {                                        \
        half8 af = *(const half8*)(xr_base + kk * 32) *                       \
                   *(const half8*)(xc_base + kk * 32);                        \
        _Pragma("unroll")                                                     \
        for (int nn = 0; nn < 4; nn++)                                        \
          acc[nn] = __builtin_amdgcn_mfma_f32_16x16x32_f16(af, Bf[nn][kk],    \
                                                           acc[nn], 0, 0, 0);  \
      }                                                                       \
      __builtin_amdgcn_s_setprio(0);                                          \
      float sc[4] = {0.f, 0.f, 0.f, 0.f};                                     \
      _Pragma("unroll")                                                       \
      for (int nn = 0; nn < 4; nn++)                                          \
        _Pragma("unroll")                                                     \
        for (int rr = 0; rr < 4; rr++)                                        \
          sc[rr] = fmaf(fmaxf(acc[nn][rr], 0.f), GB[nn], sc[rr]);             \
      _Pragma("unroll")                                                       \
      for (int rr = 0; rr < 4; rr++) sc[rr] = row_sum16(sc[rr]);              \
      wm = fmaxf(wm, fmaxf(fmaxf(sc[0], sc[1]), fmaxf(sc[2], sc[3])));        \
      if (u == 0)                                                             \
        *(f32x4*)&SPB[t * 16 + q * 4] = (f32x4){sc[0], sc[1], sc[2], sc[3]};  \
    }                                                                         \
    wm = fmaxf(wm, __shfl_xor(wm, 16, 64));                                   \
    wm = fmaxf(wm, __shfl_xor(wm, 32, 64));                                   \
    if (lane == 0) RMAXP[wave] = wm;                                          \
  }

// ---- S: exp with upper-bound shift M^ = max(sp0)+max(sp1), scatter, sum ----
// Uniform shift >= true max: softmax ratio exact; overshoot only scales by
// e^-delta (delta ~ 10-15 here, harmless in fp32).  [validated in R5]
#define SPH(PARM)                                                             \
  {                                                                           \
    const float Mh = fmaxf(rmax[PARM][0], rmax[PARM][2]) +                    \
                     fmaxf(rmax[PARM][1], rmax[PARM][3]);                     \
    float s0 = sp[PARM][0][tid] + sp[PARM][1][tid];                           \
    float s1 = sp[PARM][0][tid + 256] + sp[PARM][1][tid + 256];               \
    float e0 = __expf(s0 - Mh);                                               \
    float e1 = __expf(s1 - Mh);                                               \
    unsigned int rc = rowcol[tid];                                            \
    attn2d[PARM][(rc & 255) * TS + ((rc >> 8) - (rc & 255) - 1)] = e0;        \
    rc = rowcol[tid + 256];                                                   \
    attn2d[PARM][(rc & 255) * TS + ((rc >> 8) - (rc & 255) - 1)] = e1;        \
    float e2 = 0.f;                                                           \
    if (tid < 16) {                                                           \
      float s2 = sp[PARM][0][tid + 512] + sp[PARM][1][tid + 512];             \
      e2 = __expf(s2 - Mh);                                                   \
      rc = rowcol[tid + 512];                                                 \
      attn2d[PARM][(rc & 255) * TS + ((rc >> 8) - (rc & 255) - 1)] = e2;      \
    }                                                                         \
    float ls = (e0 + e1) + e2;                                                \
    _Pragma("unroll")                                                         \
    for (int off = 32; off >= 1; off >>= 1) ls += __shfl_xor(ls, off, 64);    \
    if (lane == 0) rsum[PARM][wave] = ls;                                     \
  }

// ---- E: barrier-free epilogue. tid<128: full 528-FMA chain for d=tid and
// direct out write; tid>=128: gnn passthrough.  [validated in R5] ------------
#define EPH(PARM, XHB, BB)                                                    \
  if (tid < 128) {                                                            \
    const float Zb = (rsum[PARM][0] + rsum[PARM][1]) +                        \
                     (rsum[PARM][2] + rsum[PARM][3]);                         \
    const int d = tid;                                                        \
    float xcol[36];                                                           \
    _Pragma("unroll")                                                         \
    for (int i = 0; i < FN; i++) xcol[i] = (float)XHB[i * XS + d];            \
    xcol[33] = 0.f; xcol[34] = 0.f; xcol[35] = 0.f;                           \
    float accv = 0.f;                                                         \
    _Pragma("unroll")                                                         \
    for (int i = 0; i < 32; i++) {                                            \
      const int L = FN - 1 - i;                                               \
      const int nf4 = (L + 3) >> 2;                                           \
      float ti = 0.f;                                                         \
      _Pragma("unroll")                                                       \
      for (int t = 0; t < nf4; t++) {                                         \
        f32x4 a4 = *(const f32x4*)&attn2d[PARM][i * TS + t * 4];              \
        ti = fmaf(a4.x, xcol[i + 1 + t * 4 + 0], ti);                         \
        ti = fmaf(a4.y, xcol[i + 1 + t * 4 + 1], ti);                         \
        ti = fmaf(a4.z, xcol[i + 1 + t * 4 + 2], ti);                         \
        ti = fmaf(a4.w, xcol[i + 1 + t * 4 + 3], ti);                         \
      }                                                                       \
      accv = fmaf(xcol[i], ti, accv);                                         \
    }                                                                         \
    out[(size_t)(BB) * (AN + DN) + AN + d] = accv * (100.0f / Zb);            \
  } else {                                                                    \
    const int a = tid - 128;                                                  \
    out[(size_t)(BB) * (AN + DN) + a] = gnn[(size_t)(BB) * AN + a];           \
  }

// R6: R4's residency (BPB=2, grid 512, 2 independent blocks/CU — the proven
// lever) + R5's barrier eliminations: in-walk max and barrier-free epilogue.
// 4 barriers per 2 batches (R4: 8).  Schedule:
//   B1(stage) | WALK(b0) | B2 | S(b0)+WALK(b1) | B3 | S(b1)+EPH(b0) | B4 | EPH(b1)
__global__ __launch_bounds__(256, 2)
void afm_kernel(const float* __restrict__ gnn, const float* __restrict__ xg,
                const float* __restrict__ Wg,  const float* __restrict__ bg,
                float* __restrict__ out)
{
  __shared__ __align__(16) _Float16 xh[2][FN * XS];     // 17.9 KB
  __shared__ __align__(16) float attn2d[2][FN * TS];    // 9.5 KB
  __shared__ __align__(16) float sp[2][2][PN];          // 8.4 KB [bi][nh][p]
  __shared__ unsigned short rowcol[PN];                 // 1 KB
  __shared__ float rmax[2][4], rsum[2][4];

  const int tid  = threadIdx.x;
  const int b0   = blockIdx.x * 2;
  const int b1   = b0 + 1;
  const int wave = tid >> 6;
  const int lane = tid & 63;
  const int q    = lane >> 4;   // quad 0..3
  const int u    = lane & 15;
  const int nh   = wave & 1;    // n-half: cols [nh*64, nh*64+64)
  const int mh   = wave >> 1;   // m-half: tiles [0,17) / [17,33)

  // -------- x loads for BOTH batches issued first ---------------------------
  f32x4 xv0[4], xv1[4];
  f32x4 xt0 = {0,0,0,0}, xt1 = {0,0,0,0};
  XLOAD(xv0, xt0, b0);
  XLOAD(xv1, xt1, b1);

  // -------- W quadrant -> Bf regs (once per 2 batches); gnn x2; bias --------
  half8 Bf[4][4];
  float g0[4], g1[4], barr[4];
  #pragma unroll
  for (int nn = 0; nn < 4; nn++) {
    const int a = nh * 64 + nn * 16 + u;
    const float* src = Wg + (size_t)a * DN + q * 8;
    #pragma unroll
    for (int kk = 0; kk < 4; kk++) {
      f32x4 w0 = *(const f32x4*)(src + kk * 32);
      f32x4 w1 = *(const f32x4*)(src + kk * 32 + 4);
      u32x4 pk;
      pk.x = pkrtz(w0.x, w0.y);
      pk.y = pkrtz(w0.z, w0.w);
      pk.z = pkrtz(w1.x, w1.y);
      pk.w = pkrtz(w1.z, w1.w);
      Bf[nn][kk] = __builtin_bit_cast(half8, pk);
      asm volatile("" : "+v"(Bf[nn][kk]));   // pin: forbid remat/sinking
    }
    g0[nn] = gnn[(size_t)b0 * AN + a];
    g1[nn] = gnn[(size_t)b1 * AN + a];
    barr[nn] = bg[a];
    asm volatile("" : "+v"(g0[nn]), "+v"(g1[nn]), "+v"(barr[nn]));
  }

  // -------- VALU-only staging overlapped with load flight -------------------
  {
    float* a2z = &attn2d[0][0];
    for (int idx = tid; idx < 2 * FN * TS; idx += 256) a2z[idx] = 0.0f;
    for (int p = tid; p < PN; p += 256) {
      int i = 0, rem = p;
      while (rem >= FN - 1 - i) { rem -= FN - 1 - i; i++; }
      rowcol[p] = (unsigned short)(i | ((i + 1 + rem) << 8));
    }
  }
  XSTORE(xv0, xt0, 0);
  XSTORE(xv1, xt1, 1);
  __syncthreads();                                      // B1

  // -------- phase 1: walk(b0) ----------------------------------------------
  WALK(xh[0], g0, (&sp[0][nh][0]), rmax[0]);
  __syncthreads();                                      // B2

  // -------- phase 2: S(b0) + walk(b1) --------------------------------------
  SPH(0);
  WALK(xh[1], g1, (&sp[1][nh][0]), rmax[1]);
  __syncthreads();                                      // B3

  // -------- phase 3: S(b1) + epilogue(b0) + out(b0) ------------------------
  SPH(1);
  EPH(0, xh[0], b0);
  __syncthreads();                                      // B4

  // -------- phase 4: epilogue(b1) + out(b1) --------------------------------
  EPH(1, xh[1], b1);
}

extern "C" void kernel_launch(void* const* d_in, const int* in_sizes, int n_in,
                              void* d_out, int out_size, void* d_ws, size_t ws_size,
                              hipStream_t stream) {
  (void)n_in; (void)out_size; (void)d_ws; (void)ws_size;
  const float* gnn  = (const float*)d_in[0];
  const float* x    = (const float*)d_in[1];
  const float* W    = (const float*)d_in[2];
  const float* bias = (const float*)d_in[3];
  float* out = (float*)d_out;
  const int Bn = in_sizes[0] / AN;   // 1024
  afm_kernel<<<dim3(Bn / 2), dim3(256), 0, stream>>>(gnn, x, W, bias, out);
}

// Round 7
// 105.228 us; speedup vs baseline: 1.2345x; 1.0256x over previous
//
#include <hip/hip_runtime.h>

// Problem constants: B=1024, F=33, D=128, A=128, P=F*(F-1)/2=528
#define FN 33
#define DN 128
#define AN 128
#define PN 528
#define XS 136     // fp16 row stride for xh in LDS (272 B, 16B-aligned, non-pow2)
#define TS 36      // float row stride for attn2d (144 B)

typedef __attribute__((ext_vector_type(8))) _Float16 half8;
typedef __attribute__((ext_vector_type(4))) float f32x4;
typedef __attribute__((ext_vector_type(4))) unsigned int u32x4;

__device__ __forceinline__ unsigned int pkrtz(float a, float b) {
  return __builtin_bit_cast(unsigned int, __builtin_amdgcn_cvt_pkrtz(a, b));
}

// max over the 16-lane DPP row via row_ror rotations
__device__ __forceinline__ float row_max16(float v) {
  v = fmaxf(v, __builtin_bit_cast(float, __builtin_amdgcn_update_dpp(0, __builtin_bit_cast(int, v), 0x128, 0xF, 0xF, false)));
  v = fmaxf(v, __builtin_bit_cast(float, __builtin_amdgcn_update_dpp(0, __builtin_bit_cast(int, v), 0x124, 0xF, 0xF, false)));
  v = fmaxf(v, __builtin_bit_cast(float, __builtin_amdgcn_update_dpp(0, __builtin_bit_cast(int, v), 0x122, 0xF, 0xF, false)));
  v = fmaxf(v, __builtin_bit_cast(float, __builtin_amdgcn_update_dpp(0, __builtin_bit_cast(int, v), 0x121, 0xF, 0xF, false)));
  return v;
}

// ---- staging: issue x loads early (pinned), convert+store later ------------
#define XLOAD(XV, XT, BB)                                                     \
  {                                                                           \
    const f32x4* xb = (const f32x4*)(xg + (size_t)(BB) * FN * DN);            \
    _Pragma("unroll")                                                         \
    for (int s = 0; s < 4; s++) {                                             \
      XV[s] = xb[tid + s * 256];                                              \
      asm volatile("" : "+v"(XV[s]));                                         \
    }                                                                         \
    if (tid < 32) XT = xb[1024 + tid];                                        \
    asm volatile("" : "+v"(XT));                                              \
  }

#define XSTORE(XV, XT, BUFI)                                                  \
  {                                                                           \
    _Pragma("unroll")                                                         \
    for (int s = 0; s < 4; s++) {                                             \
      const int idx = tid + s * 256;                                          \
      const int i = idx >> 5, d0 = (idx & 31) << 2;                           \
      *(uint2*)&xh[BUFI][i * XS + d0] =                                       \
          make_uint2(pkrtz(XV[s].x, XV[s].y), pkrtz(XV[s].z, XV[s].w));       \
    }                                                                         \
    if (tid < 32) {                                                           \
      const int idx = 1024 + tid;                                             \
      const int i = idx >> 5, d0 = (idx & 31) << 2;                           \
      *(uint2*)&xh[BUFI][i * XS + d0] =                                       \
          make_uint2(pkrtz(XT.x, XT.y), pkrtz(XT.z, XT.w));                   \
    }                                                                         \
  }

// ---- WALK (operand-swapped): acc = mfma(Bf, Af, acc) computes fm^T:
// lane(q,u) holds fm[p=u][a = nh*64 + nn*16 + q*4 + rr]. Bias pre-loaded in
// acc init (acc[nn]=bq[nn], zero VALU). Score p=u is lane-local relu-dot over
// 16 a-values (4 indep FMA chains) + 2 shfl_xor to sum the 4 q-groups.
// Replaces 16 DPP + 16 v_add per tile with 2 shfl + 2 add.
#define WALK(XHB, GQ, SPB, RMAXP)                                             \
  {                                                                           \
    const int t_beg = mh ? 17 : 0;                                            \
    const int t_end = mh ? 33 : 17;                                           \
    float wm = -3.4e38f;                                                      \
    unsigned int rc_next = rowcol[t_beg * 16 + u];                            \
    for (int t = t_beg; t < t_end; ++t) {                                     \
      const unsigned int rc = rc_next;                                        \
      if (t + 1 < t_end) rc_next = rowcol[(t + 1) * 16 + u];                  \
      const int r = rc & 255, c = rc >> 8;                                    \
      const _Float16* xr_base = &XHB[r * XS + q * 8];                         \
      const _Float16* xc_base = &XHB[c * XS + q * 8];                         \
      f32x4 acc[4];                                                           \
      _Pragma("unroll")                                                       \
      for (int nn = 0; nn < 4; nn++) acc[nn] = bq[nn];                        \
      __builtin_amdgcn_s_setprio(1);                                          \
      _Pragma("unroll")                                                       \
      for (int kk = 0; kk < 4; kk++) {                                        \
        half8 af = *(const half8*)(xr_base + kk * 32) *                       \
                   *(const half8*)(xc_base + kk * 32);                        \
        _Pragma("unroll")                                                     \
        for (int nn = 0; nn < 4; nn++)                                        \
          acc[nn] = __builtin_amdgcn_mfma_f32_16x16x32_f16(Bf[nn][kk], af,    \
                                                           acc[nn], 0, 0, 0);  \
      }                                                                       \
      __builtin_amdgcn_s_setprio(0);                                          \
      float sa0 = 0.f, sa1 = 0.f, sa2 = 0.f, sa3 = 0.f;                       \
      sa0 = fmaf(fmaxf(acc[0][0], 0.f), GQ[0].x, sa0);                        \
      sa0 = fmaf(fmaxf(acc[0][1], 0.f), GQ[0].y, sa0);                        \
      sa0 = fmaf(fmaxf(acc[0][2], 0.f), GQ[0].z, sa0);                        \
      sa0 = fmaf(fmaxf(acc[0][3], 0.f), GQ[0].w, sa0);                        \
      sa1 = fmaf(fmaxf(acc[1][0], 0.f), GQ[1].x, sa1);                        \
      sa1 = fmaf(fmaxf(acc[1][1], 0.f), GQ[1].y, sa1);                        \
      sa1 = fmaf(fmaxf(acc[1][2], 0.f), GQ[1].z, sa1);                        \
      sa1 = fmaf(fmaxf(acc[1][3], 0.f), GQ[1].w, sa1);                        \
      sa2 = fmaf(fmaxf(acc[2][0], 0.f), GQ[2].x, sa2);                        \
      sa2 = fmaf(fmaxf(acc[2][1], 0.f), GQ[2].y, sa2);                        \
      sa2 = fmaf(fmaxf(acc[2][2], 0.f), GQ[2].z, sa2);                        \
      sa2 = fmaf(fmaxf(acc[2][3], 0.f), GQ[2].w, sa2);                        \
      sa3 = fmaf(fmaxf(acc[3][0], 0.f), GQ[3].x, sa3);                        \
      sa3 = fmaf(fmaxf(acc[3][1], 0.f), GQ[3].y, sa3);                        \
      sa3 = fmaf(fmaxf(acc[3][2], 0.f), GQ[3].z, sa3);                        \
      sa3 = fmaf(fmaxf(acc[3][3], 0.f), GQ[3].w, sa3);                        \
      float s = (sa0 + sa1) + (sa2 + sa3);                                    \
      s += __shfl_xor(s, 16, 64);                                             \
      s += __shfl_xor(s, 32, 64);                                             \
      wm = fmaxf(wm, s);                                                      \
      if (lane < 16) SPB[t * 16 + lane] = s;                                  \
    }                                                                         \
    wm = row_max16(wm);                                                       \
    if (lane == 0) RMAXP[wave] = wm;                                          \
  }

// ---- S: exp with upper-bound shift M^ = max(sp0)+max(sp1), scatter, sum ----
// Uniform shift >= true max: softmax ratio exact (validated R5/R6).
#define SPH(PARM)                                                             \
  {                                                                           \
    const float Mh = fmaxf(rmax[PARM][0], rmax[PARM][2]) +                    \
                     fmaxf(rmax[PARM][1], rmax[PARM][3]);                     \
    float s0 = sp[PARM][0][tid] + sp[PARM][1][tid];                           \
    float s1 = sp[PARM][0][tid + 256] + sp[PARM][1][tid + 256];               \
    float e0 = __expf(s0 - Mh);                                               \
    float e1 = __expf(s1 - Mh);                                               \
    unsigned int rc = rowcol[tid];                                            \
    attn2d[PARM][(rc & 255) * TS + ((rc >> 8) - (rc & 255) - 1)] = e0;        \
    rc = rowcol[tid + 256];                                                   \
    attn2d[PARM][(rc & 255) * TS + ((rc >> 8) - (rc & 255) - 1)] = e1;        \
    float e2 = 0.f;                                                           \
    if (tid < 16) {                                                           \
      float s2 = sp[PARM][0][tid + 512] + sp[PARM][1][tid + 512];             \
      e2 = __expf(s2 - Mh);                                                   \
      rc = rowcol[tid + 512];                                                 \
      attn2d[PARM][(rc & 255) * TS + ((rc >> 8) - (rc & 255) - 1)] = e2;      \
    }                                                                         \
    float ls = (e0 + e1) + e2;                                                \
    _Pragma("unroll")                                                         \
    for (int off = 32; off >= 1; off >>= 1) ls += __shfl_xor(ls, off, 64);    \
    if (lane == 0) rsum[PARM][wave] = ls;                                     \
  }

// ---- EPI: R4's balanced h-split (256 threads, ~270 FMA each) -> part[PARM].
#define EPI(PARM, XHB)                                                        \
  {                                                                           \
    const int d = tid & 127;                                                  \
    const int h = tid >> 7;                                                   \
    float xcol[36];                                                           \
    _Pragma("unroll")                                                         \
    for (int i = 0; i < FN; i++) xcol[i] = (float)XHB[i * XS + d];            \
    xcol[33] = 0.f; xcol[34] = 0.f; xcol[35] = 0.f;                           \
    float accv = 0.f;                                                         \
    _Pragma("unroll")                                                         \
    for (int i = 0; i < 32; i++) {                                            \
      if ((i & 1) != h) continue;                                             \
      const int L = FN - 1 - i;                                               \
      const int nf4 = (L + 3) >> 2;                                           \
      float ti = 0.f;                                                         \
      _Pragma("unroll")                                                       \
      for (int t = 0; t < nf4; t++) {                                         \
        f32x4 a4 = *(const f32x4*)&attn2d[PARM][i * TS + t * 4];              \
        ti = fmaf(a4.x, xcol[i + 1 + t * 4 + 0], ti);                         \
        ti = fmaf(a4.y, xcol[i + 1 + t * 4 + 1], ti);                         \
        ti = fmaf(a4.z, xcol[i + 1 + t * 4 + 2], ti);                         \
        ti = fmaf(a4.w, xcol[i + 1 + t * 4 + 3], ti);                         \
      }                                                                       \
      accv = fmaf(xcol[i], ti, accv);                                         \
    }                                                                         \
    part[PARM][tid] = accv;                                                   \
  }

#define OUTW(PARM, BB)                                                        \
  if (tid < 128) {                                                            \
    const float Zb = (rsum[PARM][0] + rsum[PARM][1]) +                        \
                     (rsum[PARM][2] + rsum[PARM][3]);                         \
    float tot = part[PARM][tid] + part[PARM][tid + 128];                      \
    out[(size_t)(BB) * (AN + DN) + AN + tid] = tot * (100.0f / Zb);           \
  } else {                                                                    \
    const int a = tid - 128;                                                  \
    out[(size_t)(BB) * (AN + DN) + a] = gnn[(size_t)(BB) * AN + a];           \
  }

// R7: R4 skeleton (BPB=2, grid 512, 2 blocks/CU, balanced EPI) + operand-
// swapped MFMA (fm^T: lane-local score dot, -29 VALU/tile) + in-walk max +
// upper-bound SPH. 5 barriers per 2 batches:
//   B1(stage) | WALK(b0) | B2 | SPH(0)+WALK(b1) | B3 | SPH(1)+EPI(b0) | B4 |
//   OUT(b0)+EPI(b1) | B5 | OUT(b1)
__global__ __launch_bounds__(256, 2)
void afm_kernel(const float* __restrict__ gnn, const float* __restrict__ xg,
                const float* __restrict__ Wg,  const float* __restrict__ bg,
                float* __restrict__ out)
{
  __shared__ __align__(16) _Float16 xh[2][FN * XS];     // 17.9 KB
  __shared__ __align__(16) float attn2d[2][FN * TS];    // 9.5 KB
  __shared__ __align__(16) float sp[2][2][PN];          // 8.4 KB [bi][nh][p]
  __shared__ __align__(16) float part[2][256];          // 2 KB
  __shared__ unsigned short rowcol[PN];                 // 1 KB
  __shared__ float rmax[2][4], rsum[2][4];

  const int tid  = threadIdx.x;
  const int b0   = blockIdx.x * 2;
  const int b1   = b0 + 1;
  const int wave = tid >> 6;
  const int lane = tid & 63;
  const int q    = lane >> 4;   // quad 0..3
  const int u    = lane & 15;
  const int nh   = wave & 1;    // n-half: cols [nh*64, nh*64+64)
  const int mh   = wave >> 1;   // m-half: tiles [0,17) / [17,33)

  // -------- x loads for BOTH batches issued first ---------------------------
  f32x4 xv0[4], xv1[4];
  f32x4 xt0 = {0,0,0,0}, xt1 = {0,0,0,0};
  XLOAD(xv0, xt0, b0);
  XLOAD(xv1, xt1, b1);

  // -------- W quadrant -> Bf regs; per-lane bias/gnn vectors ----------------
  // Bf[nn][kk]: lane holds W[a = nh*64+nn*16+u][k = kk*32+q*8 .. +8]
  // bq/gq[nn]: lane holds {bias,gnn}[a = nh*64+nn*16+q*4 .. +4] (fm^T layout)
  half8 Bf[4][4];
  f32x4 bq[4], g0q[4], g1q[4];
  #pragma unroll
  for (int nn = 0; nn < 4; nn++) {
    const int a = nh * 64 + nn * 16 + u;
    const float* src = Wg + (size_t)a * DN + q * 8;
    #pragma unroll
    for (int kk = 0; kk < 4; kk++) {
      f32x4 w0 = *(const f32x4*)(src + kk * 32);
      f32x4 w1 = *(const f32x4*)(src + kk * 32 + 4);
      u32x4 pk;
      pk.x = pkrtz(w0.x, w0.y);
      pk.y = pkrtz(w0.z, w0.w);
      pk.z = pkrtz(w1.x, w1.y);
      pk.w = pkrtz(w1.z, w1.w);
      Bf[nn][kk] = __builtin_bit_cast(half8, pk);
      asm volatile("" : "+v"(Bf[nn][kk]));   // pin: forbid remat/sinking
    }
    const int abase = nh * 64 + nn * 16 + q * 4;
    bq[nn]  = *(const f32x4*)&bg[abase];
    g0q[nn] = *(const f32x4*)&gnn[(size_t)b0 * AN + abase];
    g1q[nn] = *(const f32x4*)&gnn[(size_t)b1 * AN + abase];
    asm volatile("" : "+v"(bq[nn]), "+v"(g0q[nn]), "+v"(g1q[nn]));
  }

  // -------- VALU-only staging overlapped with load flight -------------------
  {
    float* a2z = &attn2d[0][0];
    for (int idx = tid; idx < 2 * FN * TS; idx += 256) a2z[idx] = 0.0f;
    for (int p = tid; p < PN; p += 256) {
      int i = 0, rem = p;
      while (rem >= FN - 1 - i) { rem -= FN - 1 - i; i++; }
      rowcol[p] = (unsigned short)(i | ((i + 1 + rem) << 8));
    }
  }
  XSTORE(xv0, xt0, 0);
  XSTORE(xv1, xt1, 1);
  __syncthreads();                                      // B1

  // -------- phase 1: walk(b0) ----------------------------------------------
  WALK(xh[0], g0q, (&sp[0][nh][0]), rmax[0]);
  __syncthreads();                                      // B2

  // -------- phase 2: S(b0) + walk(b1) --------------------------------------
  SPH(0);
  WALK(xh[1], g1q, (&sp[1][nh][0]), rmax[1]);
  __syncthreads();                                      // B3

  // -------- phase 3: S(b1) + epilogue-partials(b0) -------------------------
  SPH(1);
  EPI(0, xh[0]);
  __syncthreads();                                      // B4

  // -------- phase 4: out(b0) + epilogue-partials(b1) -----------------------
  OUTW(0, b0);
  EPI(1, xh[1]);
  __syncthreads();                                      // B5

  // -------- phase 5: out(b1) -----------------------------------------------
  OUTW(1, b1);
}

extern "C" void kernel_launch(void* const* d_in, const int* in_sizes, int n_in,
                              void* d_out, int out_size, void* d_ws, size_t ws_size,
                              hipStream_t stream) {
  (void)n_in; (void)out_size; (void)d_ws; (void)ws_size;
  const float* gnn  = (const float*)d_in[0];
  const float* x    = (const float*)d_in[1];
  const float* W    = (const float*)d_in[2];
  const float* bias = (const float*)d_in[3];
  float* out = (float*)d_out;
  const int Bn = in_sizes[0] / AN;   // 1024
  afm_kernel<<<dim3(Bn / 2), dim3(256), 0, stream>>>(gnn, x, W, bias, out);
}

// Round 8
// 104.818 us; speedup vs baseline: 1.2393x; 1.0039x over previous
//
#include <hip/hip_runtime.h>

// Problem constants: B=1024, F=33, D=128, A=128, P=F*(F-1)/2=528
#define FN 33
#define DN 128
#define AN 128
#define PN 528
#define XS 136     // fp16 row stride for xh in LDS (272 B, 16B-aligned, non-pow2)
#define TS 36      // float row stride for attn2d (144 B)

typedef __attribute__((ext_vector_type(8))) _Float16 half8;
typedef __attribute__((ext_vector_type(4))) float f32x4;
typedef __attribute__((ext_vector_type(4))) unsigned int u32x4;

__device__ __forceinline__ unsigned int pkrtz(float a, float b) {
  return __builtin_bit_cast(unsigned int, __builtin_amdgcn_cvt_pkrtz(a, b));
}

// max over the 16-lane DPP row via row_ror rotations (VALU pipe)
__device__ __forceinline__ float row_max16(float v) {
  v = fmaxf(v, __builtin_bit_cast(float, __builtin_amdgcn_update_dpp(0, __builtin_bit_cast(int, v), 0x128, 0xF, 0xF, false)));
  v = fmaxf(v, __builtin_bit_cast(float, __builtin_amdgcn_update_dpp(0, __builtin_bit_cast(int, v), 0x124, 0xF, 0xF, false)));
  v = fmaxf(v, __builtin_bit_cast(float, __builtin_amdgcn_update_dpp(0, __builtin_bit_cast(int, v), 0x122, 0xF, 0xF, false)));
  v = fmaxf(v, __builtin_bit_cast(float, __builtin_amdgcn_update_dpp(0, __builtin_bit_cast(int, v), 0x121, 0xF, 0xF, false)));
  return v;
}

// ---- staging: issue x loads early (pinned), convert+store later ------------
#define XLOAD(XV, XT, BB)                                                     \
  {                                                                           \
    const f32x4* xb = (const f32x4*)(xg + (size_t)(BB) * FN * DN);            \
    _Pragma("unroll")                                                         \
    for (int s = 0; s < 4; s++) {                                             \
      XV[s] = xb[tid + s * 256];                                              \
      asm volatile("" : "+v"(XV[s]));                                         \
    }                                                                         \
    if (tid < 32) XT = xb[1024 + tid];                                        \
    asm volatile("" : "+v"(XT));                                              \
  }

#define XSTORE(XV, XT, BUFI)                                                  \
  {                                                                           \
    _Pragma("unroll")                                                         \
    for (int s = 0; s < 4; s++) {                                             \
      const int idx = tid + s * 256;                                          \
      const int i = idx >> 5, d0 = (idx & 31) << 2;                           \
      *(uint2*)&xh[BUFI][i * XS + d0] =                                       \
          make_uint2(pkrtz(XV[s].x, XV[s].y), pkrtz(XV[s].z, XV[s].w));       \
    }                                                                         \
    if (tid < 32) {                                                           \
      const int idx = 1024 + tid;                                             \
      const int i = idx >> 5, d0 = (idx & 31) << 2;                           \
      *(uint2*)&xh[BUFI][i * XS + d0] =                                       \
          make_uint2(pkrtz(XT.x, XT.y), pkrtz(XT.z, XT.w));                   \
    }                                                                         \
  }

// ---- WALK (operand-swapped MFMA, validated R7): acc = mfma(Bf, Af, acc)
// computes fm^T: lane(q,u) holds fm[p=u][a = nh*64 + nn*16 + q*4 + rr].
// Lane-local relu-dot over its 16 a-values (4 indep FMA chains), then ONE
// shfl_xor(16) pair-sum (q-pairs {0,1},{2,3}); the 4-way group sum is
// deferred to SPH via sp4[parity][group = nh*2+qh][p].  Removes R7's second
// serial ds_bpermute per tile.  wm tracks the per-group running max.
#define WALK(XHB, GQ, SPB, RMAXP)                                             \
  {                                                                           \
    const int t_beg = mh ? 17 : 0;                                            \
    const int t_end = mh ? 33 : 17;                                           \
    float wm = -3.4e38f;                                                      \
    unsigned int rc_next = rowcol[t_beg * 16 + u];                            \
    for (int t = t_beg; t < t_end; ++t) {                                     \
      const unsigned int rc = rc_next;                                        \
      if (t + 1 < t_end) rc_next = rowcol[(t + 1) * 16 + u];                  \
      const int r = rc & 255, c = rc >> 8;                                    \
      const _Float16* xr_base = &XHB[r * XS + q * 8];                         \
      const _Float16* xc_base = &XHB[c * XS + q * 8];                         \
      f32x4 acc[4];                                                           \
      _Pragma("unroll")                                                       \
      for (int nn = 0; nn < 4; nn++) acc[nn] = bq[nn];                        \
      __builtin_amdgcn_s_setprio(1);                                          \
      _Pragma("unroll")                                                       \
      for (int kk = 0; kk < 4; kk++) {                                        \
        half8 af = *(const half8*)(xr_base + kk * 32) *                       \
                   *(const half8*)(xc_base + kk * 32);                        \
        _Pragma("unroll")                                                     \
        for (int nn = 0; nn < 4; nn++)                                        \
          acc[nn] = __builtin_amdgcn_mfma_f32_16x16x32_f16(Bf[nn][kk], af,    \
                                                           acc[nn], 0, 0, 0);  \
      }                                                                       \
      __builtin_amdgcn_s_setprio(0);                                          \
      float sa0 = 0.f, sa1 = 0.f, sa2 = 0.f, sa3 = 0.f;                       \
      sa0 = fmaf(fmaxf(acc[0][0], 0.f), GQ[0].x, sa0);                        \
      sa0 = fmaf(fmaxf(acc[0][1], 0.f), GQ[0].y, sa0);                        \
      sa0 = fmaf(fmaxf(acc[0][2], 0.f), GQ[0].z, sa0);                        \
      sa0 = fmaf(fmaxf(acc[0][3], 0.f), GQ[0].w, sa0);                        \
      sa1 = fmaf(fmaxf(acc[1][0], 0.f), GQ[1].x, sa1);                        \
      sa1 = fmaf(fmaxf(acc[1][1], 0.f), GQ[1].y, sa1);                        \
      sa1 = fmaf(fmaxf(acc[1][2], 0.f), GQ[1].z, sa1);                        \
      sa1 = fmaf(fmaxf(acc[1][3], 0.f), GQ[1].w, sa1);                        \
      sa2 = fmaf(fmaxf(acc[2][0], 0.f), GQ[2].x, sa2);                        \
      sa2 = fmaf(fmaxf(acc[2][1], 0.f), GQ[2].y, sa2);                        \
      sa2 = fmaf(fmaxf(acc[2][2], 0.f), GQ[2].z, sa2);                        \
      sa2 = fmaf(fmaxf(acc[2][3], 0.f), GQ[2].w, sa2);                        \
      sa3 = fmaf(fmaxf(acc[3][0], 0.f), GQ[3].x, sa3);                        \
      sa3 = fmaf(fmaxf(acc[3][1], 0.f), GQ[3].y, sa3);                        \
      sa3 = fmaf(fmaxf(acc[3][2], 0.f), GQ[3].z, sa3);                        \
      sa3 = fmaf(fmaxf(acc[3][3], 0.f), GQ[3].w, sa3);                        \
      float s = (sa0 + sa1) + (sa2 + sa3);                                    \
      s += __shfl_xor(s, 16, 64);        /* q-pair sum: ONE bperm */          \
      wm = fmaxf(wm, s);                                                      \
      if ((q & 1) == 0)                                                       \
        SPB[(nh * 2 + (q >> 1)) * PN + t * 16 + u] = s;                       \
    }                                                                         \
    wm = row_max16(wm);                                                       \
    if (lane == 0)  RMAXP[wave * 2]     = wm;   /* group (nh, qh=0) */        \
    if (lane == 32) RMAXP[wave * 2 + 1] = wm;   /* group (nh, qh=1) */        \
  }

// ---- S: exp with upper-bound shift M^ = sum over 4 groups of
// max-over-mh(group max). Uniform shift >= true max: softmax ratio exact
// (shift-invariance validated R5/R6/R7); overshoot e^-delta ~1e-7..1e-11,
// fp32-safe.  s = sum of the 4 group partials from sp4.
#define SPH(PARM)                                                             \
  {                                                                           \
    const float Mh =                                                          \
        (fmaxf(rmax[PARM][0], rmax[PARM][4]) +                                \
         fmaxf(rmax[PARM][1], rmax[PARM][5])) +                               \
        (fmaxf(rmax[PARM][2], rmax[PARM][6]) +                                \
         fmaxf(rmax[PARM][3], rmax[PARM][7]));                                \
    float s0 = (sp[PARM][0][tid] + sp[PARM][1][tid]) +                        \
               (sp[PARM][2][tid] + sp[PARM][3][tid]);                         \
    float s1 = (sp[PARM][0][tid + 256] + sp[PARM][1][tid + 256]) +            \
               (sp[PARM][2][tid + 256] + sp[PARM][3][tid + 256]);             \
    float e0 = __expf(s0 - Mh);                                               \
    float e1 = __expf(s1 - Mh);                                               \
    unsigned int rc = rowcol[tid];                                            \
    attn2d[PARM][(rc & 255) * TS + ((rc >> 8) - (rc & 255) - 1)] = e0;        \
    rc = rowcol[tid + 256];                                                   \
    attn2d[PARM][(rc & 255) * TS + ((rc >> 8) - (rc & 255) - 1)] = e1;        \
    float e2 = 0.f;                                                           \
    if (tid < 16) {                                                           \
      float s2 = (sp[PARM][0][tid + 512] + sp[PARM][1][tid + 512]) +          \
                 (sp[PARM][2][tid + 512] + sp[PARM][3][tid + 512]);           \
      e2 = __expf(s2 - Mh);                                                   \
      rc = rowcol[tid + 512];                                                 \
      attn2d[PARM][(rc & 255) * TS + ((rc >> 8) - (rc & 255) - 1)] = e2;      \
    }                                                                         \
    float ls = (e0 + e1) + e2;                                                \
    _Pragma("unroll")                                                         \
    for (int off = 32; off >= 1; off >>= 1) ls += __shfl_xor(ls, off, 64);    \
    if (lane == 0) rsum[PARM][wave] = ls;                                     \
  }

// ---- EPI: R4's balanced h-split (256 threads, ~270 FMA each) -> part[PARM].
#define EPI(PARM, XHB)                                                        \
  {                                                                           \
    const int d = tid & 127;                                                  \
    const int h = tid >> 7;                                                   \
    float xcol[36];                                                           \
    _Pragma("unroll")                                                         \
    for (int i = 0; i < FN; i++) xcol[i] = (float)XHB[i * XS + d];            \
    xcol[33] = 0.f; xcol[34] = 0.f; xcol[35] = 0.f;                           \
    float accv = 0.f;                                                         \
    _Pragma("unroll")                                                         \
    for (int i = 0; i < 32; i++) {                                            \
      if ((i & 1) != h) continue;                                             \
      const int L = FN - 1 - i;                                               \
      const int nf4 = (L + 3) >> 2;                                           \
      float ti = 0.f;                                                         \
      _Pragma("unroll")                                                       \
      for (int t = 0; t < nf4; t++) {                                         \
        f32x4 a4 = *(const f32x4*)&attn2d[PARM][i * TS + t * 4];              \
        ti = fmaf(a4.x, xcol[i + 1 + t * 4 + 0], ti);                         \
        ti = fmaf(a4.y, xcol[i + 1 + t * 4 + 1], ti);                         \
        ti = fmaf(a4.z, xcol[i + 1 + t * 4 + 2], ti);                         \
        ti = fmaf(a4.w, xcol[i + 1 + t * 4 + 3], ti);                         \
      }                                                                       \
      accv = fmaf(xcol[i], ti, accv);                                         \
    }                                                                         \
    part[PARM][tid] = accv;                                                   \
  }

#define OUTW(PARM, BB)                                                        \
  if (tid < 128) {                                                            \
    const float Zb = (rsum[PARM][0] + rsum[PARM][1]) +                        \
                     (rsum[PARM][2] + rsum[PARM][3]);                         \
    float tot = part[PARM][tid] + part[PARM][tid + 128];                      \
    out[(size_t)(BB) * (AN + DN) + AN + tid] = tot * (100.0f / Zb);           \
  } else {                                                                    \
    const int a = tid - 128;                                                  \
    out[(size_t)(BB) * (AN + DN) + a] = gnn[(size_t)(BB) * AN + a];           \
  }

// R8: R7 (best-scored) with its serial cross-lane latency removed: one
// shfl_xor per tile instead of two; 4-way group sum deferred to SPH via
// sp4 LDS partials.  Same 5-barrier BPB=2 schedule:
//   B1(stage) | WALK(b0) | B2 | SPH(0)+WALK(b1) | B3 | SPH(1)+EPI(b0) | B4 |
//   OUT(b0)+EPI(b1) | B5 | OUT(b1)
__global__ __launch_bounds__(256, 2)
void afm_kernel(const float* __restrict__ gnn, const float* __restrict__ xg,
                const float* __restrict__ Wg,  const float* __restrict__ bg,
                float* __restrict__ out)
{
  __shared__ __align__(16) _Float16 xh[2][FN * XS];     // 17.9 KB
  __shared__ __align__(16) float attn2d[2][FN * TS];    // 9.5 KB
  __shared__ __align__(16) float sp[2][4][PN];          // 16.9 KB [bi][group][p]
  __shared__ __align__(16) float part[2][256];          // 2 KB
  __shared__ unsigned short rowcol[PN];                 // 1 KB
  __shared__ float rmax[2][8], rsum[2][4];

  const int tid  = threadIdx.x;
  const int b0   = blockIdx.x * 2;
  const int b1   = b0 + 1;
  const int wave = tid >> 6;
  const int lane = tid & 63;
  const int q    = lane >> 4;   // quad 0..3
  const int u    = lane & 15;
  const int nh   = wave & 1;    // n-half: cols [nh*64, nh*64+64)
  const int mh   = wave >> 1;   // m-half: tiles [0,17) / [17,33)

  // -------- x loads for BOTH batches issued first ---------------------------
  f32x4 xv0[4], xv1[4];
  f32x4 xt0 = {0,0,0,0}, xt1 = {0,0,0,0};
  XLOAD(xv0, xt0, b0);
  XLOAD(xv1, xt1, b1);

  // -------- W quadrant -> Bf regs; per-lane bias/gnn vectors ----------------
  // Bf[nn][kk]: lane holds W[a = nh*64+nn*16+u][k = kk*32+q*8 .. +8]
  // bq/gq[nn]: lane holds {bias,gnn}[a = nh*64+nn*16+q*4 .. +4] (fm^T layout)
  half8 Bf[4][4];
  f32x4 bq[4], g0q[4], g1q[4];
  #pragma unroll
  for (int nn = 0; nn < 4; nn++) {
    const int a = nh * 64 + nn * 16 + u;
    const float* src = Wg + (size_t)a * DN + q * 8;
    #pragma unroll
    for (int kk = 0; kk < 4; kk++) {
      f32x4 w0 = *(const f32x4*)(src + kk * 32);
      f32x4 w1 = *(const f32x4*)(src + kk * 32 + 4);
      u32x4 pk;
      pk.x = pkrtz(w0.x, w0.y);
      pk.y = pkrtz(w0.z, w0.w);
      pk.z = pkrtz(w1.x, w1.y);
      pk.w = pkrtz(w1.z, w1.w);
      Bf[nn][kk] = __builtin_bit_cast(half8, pk);
      asm volatile("" : "+v"(Bf[nn][kk]));   // pin: forbid remat/sinking
    }
    const int abase = nh * 64 + nn * 16 + q * 4;
    bq[nn]  = *(const f32x4*)&bg[abase];
    g0q[nn] = *(const f32x4*)&gnn[(size_t)b0 * AN + abase];
    g1q[nn] = *(const f32x4*)&gnn[(size_t)b1 * AN + abase];
    asm volatile("" : "+v"(bq[nn]), "+v"(g0q[nn]), "+v"(g1q[nn]));
  }

  // -------- VALU-only staging overlapped with load flight -------------------
  {
    float* a2z = &attn2d[0][0];
    for (int idx = tid; idx < 2 * FN * TS; idx += 256) a2z[idx] = 0.0f;
    for (int p = tid; p < PN; p += 256) {
      int i = 0, rem = p;
      while (rem >= FN - 1 - i) { rem -= FN - 1 - i; i++; }
      rowcol[p] = (unsigned short)(i | ((i + 1 + rem) << 8));
    }
  }
  XSTORE(xv0, xt0, 0);
  XSTORE(xv1, xt1, 1);
  __syncthreads();                                      // B1

  // -------- phase 1: walk(b0) ----------------------------------------------
  WALK(xh[0], g0q, (&sp[0][0][0]), rmax[0]);
  __syncthreads();                                      // B2

  // -------- phase 2: S(b0) + walk(b1) --------------------------------------
  SPH(0);
  WALK(xh[1], g1q, (&sp[1][0][0]), rmax[1]);
  __syncthreads();                                      // B3

  // -------- phase 3: S(b1) + epilogue-partials(b0) -------------------------
  SPH(1);
  EPI(0, xh[0]);
  __syncthreads();                                      // B4

  // -------- phase 4: out(b0) + epilogue-partials(b1) -----------------------
  OUTW(0, b0);
  EPI(1, xh[1]);
  __syncthreads();                                      // B5

  // -------- phase 5: out(b1) -----------------------------------------------
  OUTW(1, b1);
}

extern "C" void kernel_launch(void* const* d_in, const int* in_sizes, int n_in,
                              void* d_out, int out_size, void* d_ws, size_t ws_size,
                              hipStream_t stream) {
  (void)n_in; (void)out_size; (void)d_ws; (void)ws_size;
  const float* gnn  = (const float*)d_in[0];
  const float* x    = (const float*)d_in[1];
  const float* W    = (const float*)d_in[2];
  const float* bias = (const float*)d_in[3];
  float* out = (float*)d_out;
  const int Bn = in_sizes[0] / AN;   // 1024
  afm_kernel<<<dim3(Bn / 2), dim3(256), 0, stream>>>(gnn, x, W, bias, out);
}

// Round 9
// 100.839 us; speedup vs baseline: 1.2882x; 1.0395x over previous
//
#include <hip/hip_runtime.h>

// Problem constants: B=1024, F=33, D=128, A=128, P=F*(F-1)/2=528
#define FN 33
#define DN 128
#define AN 128
#define PN 528
#define XS 136     // fp16 row stride for xh in LDS (272 B, 16B-aligned, non-pow2)
#define TS 36      // float row stride for attn2d (144 B)

typedef __attribute__((ext_vector_type(8))) _Float16 half8;
typedef __attribute__((ext_vector_type(4))) float f32x4;
typedef __attribute__((ext_vector_type(4))) unsigned int u32x4;

__device__ __forceinline__ unsigned int pkrtz(float a, float b) {
  return __builtin_bit_cast(unsigned int, __builtin_amdgcn_cvt_pkrtz(a, b));
}

// max over the 16-lane DPP row via row_ror rotations (VALU pipe)
__device__ __forceinline__ float row_max16(float v) {
  v = fmaxf(v, __builtin_bit_cast(float, __builtin_amdgcn_update_dpp(0, __builtin_bit_cast(int, v), 0x128, 0xF, 0xF, false)));
  v = fmaxf(v, __builtin_bit_cast(float, __builtin_amdgcn_update_dpp(0, __builtin_bit_cast(int, v), 0x124, 0xF, 0xF, false)));
  v = fmaxf(v, __builtin_bit_cast(float, __builtin_amdgcn_update_dpp(0, __builtin_bit_cast(int, v), 0x122, 0xF, 0xF, false)));
  v = fmaxf(v, __builtin_bit_cast(float, __builtin_amdgcn_update_dpp(0, __builtin_bit_cast(int, v), 0x121, 0xF, 0xF, false)));
  return v;
}

// ---- staging: issue x loads early (pinned), convert+store later ------------
#define XLOAD(XV, XT, BB)                                                     \
  {                                                                           \
    const f32x4* xb = (const f32x4*)(xg + (size_t)(BB) * FN * DN);            \
    _Pragma("unroll")                                                         \
    for (int s = 0; s < 4; s++) {                                             \
      XV[s] = xb[tid + s * 256];                                              \
      asm volatile("" : "+v"(XV[s]));                                         \
    }                                                                         \
    if (tid < 32) XT = xb[1024 + tid];                                        \
    asm volatile("" : "+v"(XT));                                              \
  }

#define XSTORE(XV, XT, BUFI)                                                  \
  {                                                                           \
    _Pragma("unroll")                                                         \
    for (int s = 0; s < 4; s++) {                                             \
      const int idx = tid + s * 256;                                          \
      const int i = idx >> 5, d0 = (idx & 31) << 2;                           \
      *(uint2*)&xh[BUFI][i * XS + d0] =                                       \
          make_uint2(pkrtz(XV[s].x, XV[s].y), pkrtz(XV[s].z, XV[s].w));       \
    }                                                                         \
    if (tid < 32) {                                                           \
      const int idx = 1024 + tid;                                             \
      const int i = idx >> 5, d0 = (idx & 31) << 2;                           \
      *(uint2*)&xh[BUFI][i * XS + d0] =                                       \
          make_uint2(pkrtz(XT.x, XT.y), pkrtz(XT.z, XT.w));                   \
    }                                                                         \
  }

// lane-local relu-dot of one fm^T accumulator set against gnn quads
// (all indices compile-time after inlining; 4 independent FMA chains)
#define RELUDOT(ACC, GQ, DST)                                                 \
  {                                                                           \
    float sa0 = 0.f, sa1 = 0.f, sa2 = 0.f, sa3 = 0.f;                         \
    sa0 = fmaf(fmaxf(ACC[0][0], 0.f), GQ[0].x, sa0);                          \
    sa0 = fmaf(fmaxf(ACC[0][1], 0.f), GQ[0].y, sa0);                          \
    sa0 = fmaf(fmaxf(ACC[0][2], 0.f), GQ[0].z, sa0);                          \
    sa0 = fmaf(fmaxf(ACC[0][3], 0.f), GQ[0].w, sa0);                          \
    sa1 = fmaf(fmaxf(ACC[1][0], 0.f), GQ[1].x, sa1);                          \
    sa1 = fmaf(fmaxf(ACC[1][1], 0.f), GQ[1].y, sa1);                          \
    sa1 = fmaf(fmaxf(ACC[1][2], 0.f), GQ[1].z, sa1);                          \
    sa1 = fmaf(fmaxf(ACC[1][3], 0.f), GQ[1].w, sa1);                          \
    sa2 = fmaf(fmaxf(ACC[2][0], 0.f), GQ[2].x, sa2);                          \
    sa2 = fmaf(fmaxf(ACC[2][1], 0.f), GQ[2].y, sa2);                          \
    sa2 = fmaf(fmaxf(ACC[2][2], 0.f), GQ[2].z, sa2);                          \
    sa2 = fmaf(fmaxf(ACC[2][3], 0.f), GQ[2].w, sa2);                          \
    sa3 = fmaf(fmaxf(ACC[3][0], 0.f), GQ[3].x, sa3);                          \
    sa3 = fmaf(fmaxf(ACC[3][1], 0.f), GQ[3].y, sa3);                          \
    sa3 = fmaf(fmaxf(ACC[3][2], 0.f), GQ[3].z, sa3);                          \
    sa3 = fmaf(fmaxf(ACC[3][3], 0.f), GQ[3].w, sa3);                          \
    DST = (sa0 + sa1) + (sa2 + sa3);                                          \
  }

// ---- S: exp with upper-bound shift M^ = sum over 4 groups of
// max-over-mh(group max). Uniform shift >= true max: softmax ratio exact
// (validated R5-R8); overshoot e^-delta fp32-safe.
#define SPH(PARM)                                                             \
  {                                                                           \
    const float Mh =                                                          \
        (fmaxf(rmax[PARM][0], rmax[PARM][4]) +                                \
         fmaxf(rmax[PARM][1], rmax[PARM][5])) +                               \
        (fmaxf(rmax[PARM][2], rmax[PARM][6]) +                                \
         fmaxf(rmax[PARM][3], rmax[PARM][7]));                                \
    float s0 = (sp[PARM][0][tid] + sp[PARM][1][tid]) +                        \
               (sp[PARM][2][tid] + sp[PARM][3][tid]);                         \
    float s1 = (sp[PARM][0][tid + 256] + sp[PARM][1][tid + 256]) +            \
               (sp[PARM][2][tid + 256] + sp[PARM][3][tid + 256]);             \
    float e0 = __expf(s0 - Mh);                                               \
    float e1 = __expf(s1 - Mh);                                               \
    unsigned int rc = rowcol[tid];                                            \
    attn2d[PARM][(rc & 255) * TS + ((rc >> 8) - (rc & 255) - 1)] = e0;        \
    rc = rowcol[tid + 256];                                                   \
    attn2d[PARM][(rc & 255) * TS + ((rc >> 8) - (rc & 255) - 1)] = e1;        \
    float e2 = 0.f;                                                           \
    if (tid < 16) {                                                           \
      float s2 = (sp[PARM][0][tid + 512] + sp[PARM][1][tid + 512]) +          \
                 (sp[PARM][2][tid + 512] + sp[PARM][3][tid + 512]);           \
      e2 = __expf(s2 - Mh);                                                   \
      rc = rowcol[tid + 512];                                                 \
      attn2d[PARM][(rc & 255) * TS + ((rc >> 8) - (rc & 255) - 1)] = e2;      \
    }                                                                         \
    float ls = (e0 + e1) + e2;                                                \
    _Pragma("unroll")                                                         \
    for (int off = 32; off >= 1; off >>= 1) ls += __shfl_xor(ls, off, 64);    \
    if (lane == 0) rsum[PARM][wave] = ls;                                     \
  }

// R9: single interleaved walk over both batches (shared rowcol/address calc,
// 8 indep MFMA chains/tile, 2 pipelined shfl_xor), SPH(0)+SPH(1) in one
// phase, direct-write EPIBOTH (bi = tid>>7 owns batch bi's full chain; no
// part[] round-trip, no out-barrier).  3 barriers per 2 batches (R8: 5).
__global__ __launch_bounds__(256, 2)
void afm_kernel(const float* __restrict__ gnn, const float* __restrict__ xg,
                const float* __restrict__ Wg,  const float* __restrict__ bg,
                float* __restrict__ out)
{
  __shared__ __align__(16) _Float16 xh[2][FN * XS];     // 17.9 KB
  __shared__ __align__(16) float attn2d[2][FN * TS];    // 9.5 KB
  __shared__ __align__(16) float sp[2][4][PN];          // 16.9 KB [bi][group][p]
  __shared__ unsigned short rowcol[PN];                 // 1 KB
  __shared__ float rmax[2][8], rsum[2][4];

  const int tid  = threadIdx.x;
  const int b0   = blockIdx.x * 2;
  const int b1   = b0 + 1;
  const int wave = tid >> 6;
  const int lane = tid & 63;
  const int q    = lane >> 4;   // quad 0..3
  const int u    = lane & 15;
  const int nh   = wave & 1;    // n-half: cols [nh*64, nh*64+64)
  const int mh   = wave >> 1;   // m-half: tiles [0,17) / [17,33)

  // -------- x loads for BOTH batches issued first ---------------------------
  f32x4 xv0[4], xv1[4];
  f32x4 xt0 = {0,0,0,0}, xt1 = {0,0,0,0};
  XLOAD(xv0, xt0, b0);
  XLOAD(xv1, xt1, b1);

  // gnn passthrough value for EPIBOTH (thread (bi,d) = (tid>>7, tid&127))
  const float gpass = gnn[(size_t)(b0 + (tid >> 7)) * AN + (tid & 127)];

  // -------- W quadrant -> Bf regs; per-lane bias/gnn vectors ----------------
  // Bf[nn][kk]: lane holds W[a = nh*64+nn*16+u][k = kk*32+q*8 .. +8]
  // bq/gq[nn]: lane holds {bias,gnn}[a = nh*64+nn*16+q*4 .. +4] (fm^T layout)
  half8 Bf[4][4];
  f32x4 bq[4], g0q[4], g1q[4];
  #pragma unroll
  for (int nn = 0; nn < 4; nn++) {
    const int a = nh * 64 + nn * 16 + u;
    const float* src = Wg + (size_t)a * DN + q * 8;
    #pragma unroll
    for (int kk = 0; kk < 4; kk++) {
      f32x4 w0 = *(const f32x4*)(src + kk * 32);
      f32x4 w1 = *(const f32x4*)(src + kk * 32 + 4);
      u32x4 pk;
      pk.x = pkrtz(w0.x, w0.y);
      pk.y = pkrtz(w0.z, w0.w);
      pk.z = pkrtz(w1.x, w1.y);
      pk.w = pkrtz(w1.z, w1.w);
      Bf[nn][kk] = __builtin_bit_cast(half8, pk);
      asm volatile("" : "+v"(Bf[nn][kk]));   // pin: forbid remat/sinking
    }
    const int abase = nh * 64 + nn * 16 + q * 4;
    bq[nn]  = *(const f32x4*)&bg[abase];
    g0q[nn] = *(const f32x4*)&gnn[(size_t)b0 * AN + abase];
    g1q[nn] = *(const f32x4*)&gnn[(size_t)b1 * AN + abase];
    asm volatile("" : "+v"(bq[nn]), "+v"(g0q[nn]), "+v"(g1q[nn]));
  }

  // -------- VALU-only staging overlapped with load flight -------------------
  {
    float* a2z = &attn2d[0][0];
    for (int idx = tid; idx < 2 * FN * TS; idx += 256) a2z[idx] = 0.0f;
    for (int p = tid; p < PN; p += 256) {
      int i = 0, rem = p;
      while (rem >= FN - 1 - i) { rem -= FN - 1 - i; i++; }
      rowcol[p] = (unsigned short)(i | ((i + 1 + rem) << 8));
    }
  }
  XSTORE(xv0, xt0, 0);
  XSTORE(xv1, xt1, 1);
  __syncthreads();                                      // B1

  // -------- phase 1: interleaved walk over b0 AND b1 ------------------------
  {
    const int t_beg = mh ? 17 : 0;
    const int t_end = mh ? 33 : 17;
    float wm0 = -3.4e38f, wm1 = -3.4e38f;
    unsigned int rc_next = rowcol[t_beg * 16 + u];
    for (int t = t_beg; t < t_end; ++t) {
      const unsigned int rc = rc_next;
      if (t + 1 < t_end) rc_next = rowcol[(t + 1) * 16 + u];
      const int off_r = (rc & 255) * XS + q * 8;     // shared by both batches
      const int off_c = (rc >> 8) * XS + q * 8;

      f32x4 a0[4], a1[4];
      #pragma unroll
      for (int nn = 0; nn < 4; nn++) { a0[nn] = bq[nn]; a1[nn] = bq[nn]; }

      __builtin_amdgcn_s_setprio(1);
      #pragma unroll
      for (int kk = 0; kk < 4; kk++) {
        half8 af0 = *(const half8*)&xh[0][off_r + kk * 32] *
                    *(const half8*)&xh[0][off_c + kk * 32];
        half8 af1 = *(const half8*)&xh[1][off_r + kk * 32] *
                    *(const half8*)&xh[1][off_c + kk * 32];
        #pragma unroll
        for (int nn = 0; nn < 4; nn++) {
          a0[nn] = __builtin_amdgcn_mfma_f32_16x16x32_f16(Bf[nn][kk], af0, a0[nn], 0, 0, 0);
          a1[nn] = __builtin_amdgcn_mfma_f32_16x16x32_f16(Bf[nn][kk], af1, a1[nn], 0, 0, 0);
        }
      }
      __builtin_amdgcn_s_setprio(0);

      float s0, s1;
      RELUDOT(a0, g0q, s0);
      RELUDOT(a1, g1q, s1);
      s0 += __shfl_xor(s0, 16, 64);      // two independent bperms: pipelined
      s1 += __shfl_xor(s1, 16, 64);
      wm0 = fmaxf(wm0, s0);
      wm1 = fmaxf(wm1, s1);
      if ((q & 1) == 0) {
        const int gidx = (nh * 2 + (q >> 1)) * PN + t * 16 + u;
        (&sp[0][0][0])[gidx] = s0;
        (&sp[1][0][0])[gidx] = s1;
      }
    }
    wm0 = row_max16(wm0);
    wm1 = row_max16(wm1);
    if (lane == 0)  { rmax[0][wave * 2]     = wm0; rmax[1][wave * 2]     = wm1; }
    if (lane == 32) { rmax[0][wave * 2 + 1] = wm0; rmax[1][wave * 2 + 1] = wm1; }
  }
  __syncthreads();                                      // B2

  // -------- phase 2: SPH(b0) + SPH(b1), independent (ILP=2) -----------------
  SPH(0);
  SPH(1);
  __syncthreads();                                      // B3

  // -------- phase 3: EPIBOTH — thread (bi,d) computes batch bi, col d -------
  {
    const int bi = tid >> 7;          // wave-uniform (waves 0,1 -> b0; 2,3 -> b1)
    const int d  = tid & 127;
    const _Float16* xhb = &xh[bi][0];
    const float* a2 = &attn2d[bi][0];
    const float Zb = (rsum[bi][0] + rsum[bi][1]) + (rsum[bi][2] + rsum[bi][3]);

    float xcol[36];
    #pragma unroll
    for (int i = 0; i < FN; i++) xcol[i] = (float)xhb[i * XS + d];
    xcol[33] = 0.f; xcol[34] = 0.f; xcol[35] = 0.f;

    float acc0 = 0.f, acc1 = 0.f;     // i-parity split accumulators (ILP)
    #pragma unroll
    for (int i = 0; i < 32; i++) {
      const int L = FN - 1 - i;                  // pairs (i, i+1+jj), jj < L
      const int nf4 = (L + 3) >> 2;
      float ti = 0.f;
      #pragma unroll
      for (int t = 0; t < nf4; t++) {
        f32x4 a4 = *(const f32x4*)&a2[i * TS + t * 4];  // pad entries are 0
        ti = fmaf(a4.x, xcol[i + 1 + t * 4 + 0], ti);
        ti = fmaf(a4.y, xcol[i + 1 + t * 4 + 1], ti);
        ti = fmaf(a4.z, xcol[i + 1 + t * 4 + 2], ti);
        ti = fmaf(a4.w, xcol[i + 1 + t * 4 + 3], ti);
      }
      if (i & 1) acc1 = fmaf(xcol[i], ti, acc1);
      else       acc0 = fmaf(xcol[i], ti, acc0);
    }
    const size_t obase = (size_t)(b0 + bi) * (AN + DN);
    out[obase + AN + d] = (acc0 + acc1) * (100.0f / Zb);
    out[obase + d] = gpass;
  }
}

extern "C" void kernel_launch(void* const* d_in, const int* in_sizes, int n_in,
                              void* d_out, int out_size, void* d_ws, size_t ws_size,
                              hipStream_t stream) {
  (void)n_in; (void)out_size; (void)d_ws; (void)ws_size;
  const float* gnn  = (const float*)d_in[0];
  const float* x    = (const float*)d_in[1];
  const float* W    = (const float*)d_in[2];
  const float* bias = (const float*)d_in[3];
  float* out = (float*)d_out;
  const int Bn = in_sizes[0] / AN;   // 1024
  afm_kernel<<<dim3(Bn / 2), dim3(256), 0, stream>>>(gnn, x, W, bias, out);
}